// Round 1
// baseline (8246.008 us; speedup 1.0000x reference)
//
#include <hip/hip_runtime.h>
#include <cstdint>

// LSTM: SEQ=512, B=64, IN=H=1024. fp32 in/out, bf16 MFMA compute, fp32 x_proj/c.
// Phase 1 (unchanged): chunked x_proj GEMM (TC=128 timesteps per chunk).
// Phase 2 (NEW): persistent cooperative kernel runs 128 timesteps per launch.
//   - grid 256 blocks (1 per CU), block = (bt in 0..3 batch-tile of 16) x (jt in 0..63 hidden-tile of 16)
//   - W_hh fragments for all 4 gates live in VGPRs (128 regs/thread) for the whole launch
//   - waves split K (wave w owns K cols [256w,256w+256)) -> disjoint h reads, partials summed via LDS
//   - c-state lives in a register across all 128 steps
//   - one agent-scope grid barrier per step (release fetch_add + relaxed spin + acquire)

typedef __bf16 bf16x8 __attribute__((ext_vector_type(8)));
typedef __bf16 bf16x4 __attribute__((ext_vector_type(4)));
typedef float  floatx4 __attribute__((ext_vector_type(4)));

#define SEQ   512
#define BATCH 64
#define HID   1024
#define GATES 4096
#define TC    128   // time-chunk for x_proj buffer (ws = B*TC*4H fp32 = 128 MB)
#define NBLK  256   // persistent grid blocks (1 per CU)

__device__ __forceinline__ float fast_sigm(float x) {
  return 1.0f / (1.0f + __expf(-x));
}
__device__ __forceinline__ float fast_tanh(float x) {
  x = fminf(15.0f, fmaxf(-15.0f, x));   // avoid inf/inf -> NaN
  float e = __expf(2.0f * x);
  return (e - 1.0f) / (e + 1.0f);
}

// ---------------- casts / small prep ----------------
__global__ void cast_f32_to_bf16_x4(const float* __restrict__ src,
                                    __bf16* __restrict__ dst, int n4) {
  int i = blockIdx.x * blockDim.x + threadIdx.x;
  if (i < n4) {
    float4 v = reinterpret_cast<const float4*>(src)[i];
    bf16x4 o;
    o[0] = (__bf16)v.x; o[1] = (__bf16)v.y; o[2] = (__bf16)v.z; o[3] = (__bf16)v.w;
    reinterpret_cast<bf16x4*>(dst)[i] = o;
  }
}

__global__ void bias_sum(const float* __restrict__ a, const float* __restrict__ b,
                         float* __restrict__ o) {
  int i = blockIdx.x * blockDim.x + threadIdx.x;
  if (i < GATES) o[i] = a[i] + b[i];
}

// ---------------- phase 1: x_proj chunk GEMM (unchanged) ----------------
__global__ __launch_bounds__(256) void gemm_xproj(
    const __bf16* __restrict__ X,    // [B*SEQ][1024] bf16
    const __bf16* __restrict__ W,    // [4096][1024] bf16 (W_ih)
    const float*  __restrict__ bias, // [4096]
    float*        __restrict__ XP,   // [B*TC][4096] fp32
    int t0) {
  __shared__ __bf16 As[128][40];   // +8 pad: 2-way bank aliasing only (free)
  __shared__ __bf16 Bs[128][40];

  const int tid  = threadIdx.x;
  const int lane = tid & 63;
  const int w    = tid >> 6;
  const int wm   = w >> 1, wn = w & 1;
  const int mt   = blockIdx.x;           // = batch b (TC==tile_M==128)
  const int n0   = blockIdx.y * 128;
  const long arow0 = (long)mt * 512 + t0;

  floatx4 acc[4][4] = {};

  for (int k0 = 0; k0 < 1024; k0 += 32) {
    __syncthreads();
#pragma unroll
    for (int r = 0; r < 2; ++r) {
      int c = tid + 256 * r;          // 512 chunks of 8 bf16 per operand
      int row = c >> 2, c8 = c & 3;
      *reinterpret_cast<uint4*>(&As[row][c8 * 8]) =
          *reinterpret_cast<const uint4*>(&X[(arow0 + row) * 1024 + k0 + c8 * 8]);
      *reinterpret_cast<uint4*>(&Bs[row][c8 * 8]) =
          *reinterpret_cast<const uint4*>(&W[(long)(n0 + row) * 1024 + k0 + c8 * 8]);
    }
    __syncthreads();

    bf16x8 a[4], b[4];
#pragma unroll
    for (int i = 0; i < 4; ++i)
      a[i] = *reinterpret_cast<const __shared__ bf16x8*>(
          &As[wm * 64 + i * 16 + (lane & 15)][(lane >> 4) * 8]);
#pragma unroll
    for (int j = 0; j < 4; ++j)
      b[j] = *reinterpret_cast<const __shared__ bf16x8*>(
          &Bs[wn * 64 + j * 16 + (lane & 15)][(lane >> 4) * 8]);
#pragma unroll
    for (int i = 0; i < 4; ++i)
#pragma unroll
      for (int j = 0; j < 4; ++j)
        acc[i][j] = __builtin_amdgcn_mfma_f32_16x16x32_bf16(a[i], b[j], acc[i][j], 0, 0, 0);
  }

#pragma unroll
  for (int i = 0; i < 4; ++i) {
    int mloc = wm * 64 + i * 16 + (lane >> 4) * 4;
#pragma unroll
    for (int j = 0; j < 4; ++j) {
      int n = n0 + wn * 64 + j * 16 + (lane & 15);
      float bn = bias[n];
#pragma unroll
      for (int r = 0; r < 4; ++r)
        XP[(long)(mt * 128 + mloc + r) * 4096 + n] = acc[i][j][r] + bn;
    }
  }
}

// ---------------- phase 2 (fallback): one timestep per launch ----------------
__global__ __launch_bounds__(256) void lstm_step(
    const __bf16* __restrict__ hin,   // [64][1024]
    __bf16*       __restrict__ hout,  // [64][1024]
    float*        __restrict__ cst,   // [64][1024] fp32
    const __bf16* __restrict__ Whh,   // [4096][1024] bf16
    const float*  __restrict__ xp,    // chunk [B*TC][4096] fp32 (bias included)
    float*        __restrict__ out,   // full output buffer
    int t) {
  __shared__ __bf16 Hs[16][1032];    // pad: stride 516 words -> 2-way only
  __shared__ __bf16 Bs[64][264];     // pad: stride 132 words -> 2-way only
  __shared__ float  Gs[4][16][17];

  const int tid  = threadIdx.x;
  const int lane = tid & 63;
  const int w    = tid >> 6;         // gate type: 0=i 1=f 2=g 3=o
  const int j0   = blockIdx.x * 16;
  const int b0   = blockIdx.y * 16;

#pragma unroll
  for (int r = 0; r < 8; ++r) {
    int c = tid + 256 * r;           // 2048 chunks of 8
    int row = c >> 7, c8 = c & 127;
    *reinterpret_cast<uint4*>(&Hs[row][c8 * 8]) =
        *reinterpret_cast<const uint4*>(&hin[(b0 + row) * 1024 + c8 * 8]);
  }

  floatx4 acc = {};
  for (int kc = 0; kc < 4; ++kc) {   // K chunks of 256
    __syncthreads();
#pragma unroll
    for (int r = 0; r < 8; ++r) {
      int c = tid + 256 * r;         // 2048 chunks of 8 (64 rows x 256)
      int rb = c >> 5, c8 = c & 31;
      int grow = (rb >> 4) * 1024 + j0 + (rb & 15);
      *reinterpret_cast<uint4*>(&Bs[rb][c8 * 8]) =
          *reinterpret_cast<const uint4*>(&Whh[(long)grow * 1024 + kc * 256 + c8 * 8]);
    }
    __syncthreads();
#pragma unroll
    for (int q = 0; q < 8; ++q) {
      bf16x8 a = *reinterpret_cast<const __shared__ bf16x8*>(
          &Hs[lane & 15][kc * 256 + q * 32 + (lane >> 4) * 8]);
      bf16x8 b = *reinterpret_cast<const __shared__ bf16x8*>(
          &Bs[w * 16 + (lane & 15)][q * 32 + (lane >> 4) * 8]);
      acc = __builtin_amdgcn_mfma_f32_16x16x32_bf16(a, b, acc, 0, 0, 0);
    }
  }

#pragma unroll
  for (int r = 0; r < 4; ++r)
    Gs[w][(lane >> 4) * 4 + r][lane & 15] = acc[r];
  __syncthreads();

  int bb = tid >> 4, jj = tid & 15;
  int b = b0 + bb, j = j0 + jj;
  int tt = t & (TC - 1);
  const float* xr = &xp[((long)b * TC + tt) * 4096 + j];
  float gi = Gs[0][bb][jj] + xr[0];
  float gf = Gs[1][bb][jj] + xr[1024];
  float gg = Gs[2][bb][jj] + xr[2048];
  float go = Gs[3][bb][jj] + xr[3072];
  float c_old = cst[b * 1024 + j];
  float c_new = fast_sigm(gf) * c_old + fast_sigm(gi) * fast_tanh(gg);
  float h_new = fast_sigm(go) * fast_tanh(c_new);
  cst[b * 1024 + j]  = c_new;
  hout[b * 1024 + j] = (__bf16)h_new;
  out[(long)b * (SEQ * HID) + (long)t * HID + j] = h_new;
  if (t == SEQ - 1) {
    out[(long)SEQ * BATCH * HID + b * HID + j] = h_new;                 // h_n
    out[(long)SEQ * BATCH * HID + BATCH * HID + b * HID + j] = c_new;   // c_n
  }
}

// ---------------- phase 2 (primary): persistent chunk kernel ----------------
// One launch runs TC=128 timesteps; grid (64 jt, 4 bt) x 256 threads.
// Wave w owns K columns [w*256, w*256+256) for all 4 gates of this block's
// (16b x 16j) square; partial gate sums exchanged through LDS.
__global__ __launch_bounds__(256, 1) void lstm_persist(
    const __bf16* __restrict__ Whh,   // [4096][1024] bf16
    const float*  __restrict__ xp,    // chunk [B*TC][4096] fp32 (bias included)
    float*        __restrict__ cst,   // [64][1024] fp32 (chunk-boundary c state)
    __bf16*       __restrict__ hbuf0, // h buffer read at even t
    __bf16*       __restrict__ hbuf1, // h buffer read at odd t
    float*        __restrict__ out,
    unsigned*     __restrict__ bar,   // zeroed before launch
    int t0) {
  __shared__ float Gp[4][4][16][17];  // [wave][gate][brow][jcol]

  const int tid  = threadIdx.x;
  const int lane = tid & 63;
  const int w    = tid >> 6;          // K-slice index
  const int j0   = blockIdx.x * 16;   // hidden tile
  const int b0   = blockIdx.y * 16;   // batch tile

  // ---- preload W_hh fragments into registers (held for all 128 steps) ----
  // B-frag for gate g, kc = w*8+k: lane holds Whh[g*1024 + j0 + (lane&15)][kc*32 + (lane>>4)*8 .. +8]
  bf16x8 wf[32];
  {
    const int r = lane & 15, q = lane >> 4;
#pragma unroll
    for (int g = 0; g < 4; ++g)
#pragma unroll
      for (int k = 0; k < 8; ++k)
        wf[g * 8 + k] = *reinterpret_cast<const bf16x8*>(
            Whh + (size_t)(g * 1024 + j0 + r) * 1024 + (w * 8 + k) * 32 + q * 8);
  }

  // ---- per-thread (b,j) ownership for the elementwise update ----
  const int bb = tid >> 4, jj = tid & 15;
  const int gb = b0 + bb, gj = j0 + jj;
  float c = cst[gb * 1024 + gj];

  // A-frag base: lane holds h[b0+(lane&15)][w*256 + k*32 + (lane>>4)*8 .. +8]
  const int arow = (b0 + (lane & 15)) * 1024 + w * 256 + ((lane >> 4) * 8);
  const float* xrow = xp + (size_t)gb * TC * 4096 + gj;
  float* orow = out + (size_t)gb * (SEQ * HID) + gj;

  for (int tt = 0; tt < TC; ++tt) {
    const int t = t0 + tt;
    const __bf16* __restrict__ hin  = (t & 1) ? hbuf1 : hbuf0;
    __bf16*       __restrict__ hout = (t & 1) ? hbuf0 : hbuf1;

    // xp loads are h-independent: issue alongside A loads, latency overlaps
    const float* xr = xrow + (size_t)tt * 4096;
    float xi = xr[0];
    float xf = xr[1024];
    float xg = xr[2048];
    float xo = xr[3072];

    // ---- h A-fragments (disjoint across waves: no staging needed) ----
    bf16x8 a[8];
#pragma unroll
    for (int k = 0; k < 8; ++k)
      a[k] = *reinterpret_cast<const bf16x8*>(hin + arow + k * 32);

    // ---- 32 MFMAs: 4 independent chains (one per gate) of depth 8 ----
    floatx4 acc[4] = {};
#pragma unroll
    for (int k = 0; k < 8; ++k)
#pragma unroll
      for (int g = 0; g < 4; ++g)
        acc[g] = __builtin_amdgcn_mfma_f32_16x16x32_bf16(a[k], wf[g * 8 + k], acc[g], 0, 0, 0);

    // ---- exchange K-slice partials through LDS ----
#pragma unroll
    for (int g = 0; g < 4; ++g)
#pragma unroll
      for (int r = 0; r < 4; ++r)
        Gp[w][g][(lane >> 4) * 4 + r][lane & 15] = acc[g][r];
    __syncthreads();

    float gi = Gp[0][0][bb][jj] + Gp[1][0][bb][jj] + Gp[2][0][bb][jj] + Gp[3][0][bb][jj] + xi;
    float gf = Gp[0][1][bb][jj] + Gp[1][1][bb][jj] + Gp[2][1][bb][jj] + Gp[3][1][bb][jj] + xf;
    float gg = Gp[0][2][bb][jj] + Gp[1][2][bb][jj] + Gp[2][2][bb][jj] + Gp[3][2][bb][jj] + xg;
    float go = Gp[0][3][bb][jj] + Gp[1][3][bb][jj] + Gp[2][3][bb][jj] + Gp[3][3][bb][jj] + xo;

    c = fast_sigm(gf) * c + fast_sigm(gi) * fast_tanh(gg);
    float h = fast_sigm(go) * fast_tanh(c);
    hout[gb * 1024 + gj] = (__bf16)h;
    orow[(size_t)t * HID] = h;
    if (t == SEQ - 1) {
      out[(size_t)SEQ * BATCH * HID + gb * HID + gj] = h;                 // h_n
      out[(size_t)SEQ * BATCH * HID + BATCH * HID + gb * HID + gj] = c;   // c_n
    }

    // ---- grid barrier: release our h writes, acquire everyone else's ----
    // (monotonic counter; release-sequence of fetch_adds + one acquire load)
    __syncthreads();                  // drains all waves' stores to L2
    if (tid == 0) {
      __hip_atomic_fetch_add(bar, 1u, __ATOMIC_RELEASE, __HIP_MEMORY_SCOPE_AGENT);
      const unsigned want = (unsigned)NBLK * (unsigned)(tt + 1);
      while (__hip_atomic_load(bar, __ATOMIC_RELAXED, __HIP_MEMORY_SCOPE_AGENT) < want) {}
      (void)__hip_atomic_load(bar, __ATOMIC_ACQUIRE, __HIP_MEMORY_SCOPE_AGENT);
    }
    __syncthreads();                  // also protects Gp reuse next step
  }

  cst[gb * 1024 + gj] = c;            // chunk-boundary state for next launch
}

// ---------------- host ----------------
extern "C" void kernel_launch(void* const* d_in, const int* in_sizes, int n_in,
                              void* d_out, int out_size, void* d_ws, size_t ws_size,
                              hipStream_t stream) {
  const float* inp = (const float*)d_in[0];
  const float* h0  = (const float*)d_in[1];
  const float* c0  = (const float*)d_in[2];
  const float* Wih = (const float*)d_in[3];
  const float* Whh = (const float*)d_in[4];
  const float* bih = (const float*)d_in[5];
  const float* bhh = (const float*)d_in[6];
  float* out = (float*)d_out;
  char* ws = (char*)d_ws;

  size_t off = 0;
  __bf16* Wih_b = (__bf16*)(ws + off); off += (size_t)GATES * HID * 2;        // 8 MB
  __bf16* Whh_b = (__bf16*)(ws + off); off += (size_t)GATES * HID * 2;        // 8 MB
  __bf16* x_b   = (__bf16*)(ws + off); off += (size_t)SEQ * BATCH * HID * 2;  // 64 MB
  float*  xp    = (float*)(ws + off);  off += (size_t)BATCH * TC * GATES * 4; // 128 MB
  float*  bias  = (float*)(ws + off);  off += (size_t)GATES * 4;
  float*  cst   = (float*)(ws + off);  off += (size_t)BATCH * HID * 4;
  __bf16* hb0   = (__bf16*)(ws + off); off += (size_t)BATCH * HID * 2;
  __bf16* hb1   = (__bf16*)(ws + off); off += (size_t)BATCH * HID * 2;
  unsigned* bar = (unsigned*)(ws + off); off += 256;                          // barrier counter
  if (ws_size < off) return;  // ws too small: fail cleanly (diagnosable)

  int n4;
  n4 = GATES * HID / 4;
  cast_f32_to_bf16_x4<<<(n4 + 255) / 256, 256, 0, stream>>>(Wih, Wih_b, n4);
  cast_f32_to_bf16_x4<<<(n4 + 255) / 256, 256, 0, stream>>>(Whh, Whh_b, n4);
  n4 = SEQ * BATCH * HID / 4;
  cast_f32_to_bf16_x4<<<(n4 + 255) / 256, 256, 0, stream>>>(inp, x_b, n4);
  n4 = BATCH * HID / 4;
  cast_f32_to_bf16_x4<<<(n4 + 255) / 256, 256, 0, stream>>>(h0, hb0, n4);
  bias_sum<<<GATES / 256, 256, 0, stream>>>(bih, bhh, bias);
  hipMemcpyAsync(cst, c0, (size_t)BATCH * HID * 4, hipMemcpyDeviceToDevice, stream);

  __bf16* hbuf[2] = {hb0, hb1};
  bool coop_ok = true;
  for (int chunk = 0; chunk < SEQ / TC; ++chunk) {
    int t0 = chunk * TC;
    gemm_xproj<<<dim3(BATCH, GATES / 128), 256, 0, stream>>>(x_b, Wih_b, bias, xp, t0);
    if (coop_ok) {
      hipMemsetAsync(bar, 0, sizeof(unsigned), stream);
      void* args[] = {(void*)&Whh_b, (void*)&xp, (void*)&cst, (void*)&hb0,
                      (void*)&hb1, (void*)&out, (void*)&bar, (void*)&t0};
      if (hipLaunchCooperativeKernel((const void*)lstm_persist, dim3(64, 4),
                                     dim3(256, 1, 1), args, 0, stream) != hipSuccess)
        coop_ok = false;
    }
    if (!coop_ok) {
      for (int tt = 0; tt < TC; ++tt) {
        int t = t0 + tt;
        lstm_step<<<dim3(HID / 16, BATCH / 16), 256, 0, stream>>>(
            hbuf[t & 1], hbuf[(t + 1) & 1], cst, Whh_b, xp, out, t);
      }
    }
  }
}

// Round 3
// 5035.647 us; speedup vs baseline: 1.6375x; 1.6375x over previous
//
#include <hip/hip_runtime.h>
#include <cstdint>

// LSTM: SEQ=512, B=64, IN=H=1024. fp32 in/out, bf16 MFMA compute, fp32 x_proj/c.
// Phase 1: chunked x_proj GEMM (TC=128 timesteps per chunk)  [unchanged]
// Phase 2: persistent cooperative kernel, 128 timesteps per launch.
//   - 4 INDEPENDENT groups of 64 blocks (batches are independent in the recurrence);
//     each group syncs only among its 64 blocks, mapped to an XCD pair.
//   - barrier = per-block arrival slots (release stores, no RMW) + master-wave
//     64-lane sweep + single release word; monotonic epochs (one memset per run).
//   - W_hh fragments pinned in VGPRs via asm (compiler sank them to memory in v1).
//   - next-step xp prefetched before the barrier spin (latency hidden).

typedef __bf16 bf16x8 __attribute__((ext_vector_type(8)));
typedef __bf16 bf16x4 __attribute__((ext_vector_type(4)));
typedef float  floatx4 __attribute__((ext_vector_type(4)));

#define SEQ   512
#define BATCH 64
#define HID   1024
#define GATES 4096
#define TC    128   // time-chunk for x_proj buffer (ws = B*TC*4H fp32 = 128 MB)
#define NBLK  256   // persistent grid blocks (1 per CU)
#define GRPB  64    // blocks per batch-group (independent sync domains)

__device__ __forceinline__ float fast_sigm(float x) {
  return 1.0f / (1.0f + __expf(-x));
}
__device__ __forceinline__ float fast_tanh(float x) {
  x = fminf(15.0f, fmaxf(-15.0f, x));   // avoid inf/inf -> NaN
  float e = __expf(2.0f * x);
  return (e - 1.0f) / (e + 1.0f);
}

// ---------------- casts / small prep ----------------
__global__ void cast_f32_to_bf16_x4(const float* __restrict__ src,
                                    __bf16* __restrict__ dst, int n4) {
  int i = blockIdx.x * blockDim.x + threadIdx.x;
  if (i < n4) {
    float4 v = reinterpret_cast<const float4*>(src)[i];
    bf16x4 o;
    o[0] = (__bf16)v.x; o[1] = (__bf16)v.y; o[2] = (__bf16)v.z; o[3] = (__bf16)v.w;
    reinterpret_cast<bf16x4*>(dst)[i] = o;
  }
}

__global__ void bias_sum(const float* __restrict__ a, const float* __restrict__ b,
                         float* __restrict__ o) {
  int i = blockIdx.x * blockDim.x + threadIdx.x;
  if (i < GATES) o[i] = a[i] + b[i];
}

// ---------------- phase 1: x_proj chunk GEMM (unchanged) ----------------
__global__ __launch_bounds__(256) void gemm_xproj(
    const __bf16* __restrict__ X,    // [B*SEQ][1024] bf16
    const __bf16* __restrict__ W,    // [4096][1024] bf16 (W_ih)
    const float*  __restrict__ bias, // [4096]
    float*        __restrict__ XP,   // [B*TC][4096] fp32
    int t0) {
  __shared__ __bf16 As[128][40];   // +8 pad: 2-way bank aliasing only (free)
  __shared__ __bf16 Bs[128][40];

  const int tid  = threadIdx.x;
  const int lane = tid & 63;
  const int w    = tid >> 6;
  const int wm   = w >> 1, wn = w & 1;
  const int mt   = blockIdx.x;           // = batch b (TC==tile_M==128)
  const int n0   = blockIdx.y * 128;
  const long arow0 = (long)mt * 512 + t0;

  floatx4 acc[4][4] = {};

  for (int k0 = 0; k0 < 1024; k0 += 32) {
    __syncthreads();
#pragma unroll
    for (int r = 0; r < 2; ++r) {
      int c = tid + 256 * r;          // 512 chunks of 8 bf16 per operand
      int row = c >> 2, c8 = c & 3;
      *reinterpret_cast<uint4*>(&As[row][c8 * 8]) =
          *reinterpret_cast<const uint4*>(&X[(arow0 + row) * 1024 + k0 + c8 * 8]);
      *reinterpret_cast<uint4*>(&Bs[row][c8 * 8]) =
          *reinterpret_cast<const uint4*>(&W[(long)(n0 + row) * 1024 + k0 + c8 * 8]);
    }
    __syncthreads();

    bf16x8 a[4], b[4];
#pragma unroll
    for (int i = 0; i < 4; ++i)
      a[i] = *reinterpret_cast<const __shared__ bf16x8*>(
          &As[wm * 64 + i * 16 + (lane & 15)][(lane >> 4) * 8]);
#pragma unroll
    for (int j = 0; j < 4; ++j)
      b[j] = *reinterpret_cast<const __shared__ bf16x8*>(
          &Bs[wn * 64 + j * 16 + (lane & 15)][(lane >> 4) * 8]);
#pragma unroll
    for (int i = 0; i < 4; ++i)
#pragma unroll
      for (int j = 0; j < 4; ++j)
        acc[i][j] = __builtin_amdgcn_mfma_f32_16x16x32_bf16(a[i], b[j], acc[i][j], 0, 0, 0);
  }

#pragma unroll
  for (int i = 0; i < 4; ++i) {
    int mloc = wm * 64 + i * 16 + (lane >> 4) * 4;
#pragma unroll
    for (int j = 0; j < 4; ++j) {
      int n = n0 + wn * 64 + j * 16 + (lane & 15);
      float bn = bias[n];
#pragma unroll
      for (int r = 0; r < 4; ++r)
        XP[(long)(mt * 128 + mloc + r) * 4096 + n] = acc[i][j][r] + bn;
    }
  }
}

// ---------------- phase 2 (fallback): one timestep per launch ----------------
__global__ __launch_bounds__(256) void lstm_step(
    const __bf16* __restrict__ hin,   // [64][1024]
    __bf16*       __restrict__ hout,  // [64][1024]
    float*        __restrict__ cst,   // [64][1024] fp32
    const __bf16* __restrict__ Whh,   // [4096][1024] bf16
    const float*  __restrict__ xp,    // chunk [B*TC][4096] fp32 (bias included)
    float*        __restrict__ out,   // full output buffer
    int t) {
  __shared__ __bf16 Hs[16][1032];
  __shared__ __bf16 Bs[64][264];
  __shared__ float  Gs[4][16][17];

  const int tid  = threadIdx.x;
  const int lane = tid & 63;
  const int w    = tid >> 6;         // gate type: 0=i 1=f 2=g 3=o
  const int j0   = blockIdx.x * 16;
  const int b0   = blockIdx.y * 16;

#pragma unroll
  for (int r = 0; r < 8; ++r) {
    int c = tid + 256 * r;           // 2048 chunks of 8
    int row = c >> 7, c8 = c & 127;
    *reinterpret_cast<uint4*>(&Hs[row][c8 * 8]) =
        *reinterpret_cast<const uint4*>(&hin[(b0 + row) * 1024 + c8 * 8]);
  }

  floatx4 acc = {};
  for (int kc = 0; kc < 4; ++kc) {   // K chunks of 256
    __syncthreads();
#pragma unroll
    for (int r = 0; r < 8; ++r) {
      int c = tid + 256 * r;         // 2048 chunks of 8 (64 rows x 256)
      int rb = c >> 5, c8 = c & 31;
      int grow = (rb >> 4) * 1024 + j0 + (rb & 15);
      *reinterpret_cast<uint4*>(&Bs[rb][c8 * 8]) =
          *reinterpret_cast<const uint4*>(&Whh[(long)grow * 1024 + kc * 256 + c8 * 8]);
    }
    __syncthreads();
#pragma unroll
    for (int q = 0; q < 8; ++q) {
      bf16x8 a = *reinterpret_cast<const __shared__ bf16x8*>(
          &Hs[lane & 15][kc * 256 + q * 32 + (lane >> 4) * 8]);
      bf16x8 b = *reinterpret_cast<const __shared__ bf16x8*>(
          &Bs[w * 16 + (lane & 15)][q * 32 + (lane >> 4) * 8]);
      acc = __builtin_amdgcn_mfma_f32_16x16x32_bf16(a, b, acc, 0, 0, 0);
    }
  }

#pragma unroll
  for (int r = 0; r < 4; ++r)
    Gs[w][(lane >> 4) * 4 + r][lane & 15] = acc[r];
  __syncthreads();

  int bb = tid >> 4, jj = tid & 15;
  int b = b0 + bb, j = j0 + jj;
  int tt = t & (TC - 1);
  const float* xr = &xp[((long)b * TC + tt) * 4096 + j];
  float gi = Gs[0][bb][jj] + xr[0];
  float gf = Gs[1][bb][jj] + xr[1024];
  float gg = Gs[2][bb][jj] + xr[2048];
  float go = Gs[3][bb][jj] + xr[3072];
  float c_old = cst[b * 1024 + j];
  float c_new = fast_sigm(gf) * c_old + fast_sigm(gi) * fast_tanh(gg);
  float h_new = fast_sigm(go) * fast_tanh(c_new);
  cst[b * 1024 + j]  = c_new;
  hout[b * 1024 + j] = (__bf16)h_new;
  out[(long)b * (SEQ * HID) + (long)t * HID + j] = h_new;
  if (t == SEQ - 1) {
    out[(long)SEQ * BATCH * HID + b * HID + j] = h_new;                 // h_n
    out[(long)SEQ * BATCH * HID + BATCH * HID + b * HID + j] = c_new;   // c_n
  }
}

// ---------------- phase 2 (primary): persistent chunk kernel ----------------
// 256 blocks = 4 independent groups (batch tiles of 16) x 64 blocks (j-tiles of 16).
// Group bt lives on XCD pair {2bt, 2bt+1}. Per-group barrier:
//   arrival: release-store epoch to own 128B-padded slot (no RMW contention)
//   master (bx==0) wave 0: 64-lane sweep of slots, then release-store epoch to rel
//   others: tid 0 polls rel, acquire fence, __syncthreads broadcast
__global__ __launch_bounds__(256, 1) void lstm_persist(
    const __bf16* __restrict__ Whh,   // [4096][1024] bf16
    const float*  __restrict__ xp,    // chunk [B*TC][4096] fp32 (bias included)
    float*        __restrict__ cst,   // [64][1024] fp32 (chunk-boundary c state)
    __bf16*       __restrict__ hbuf0, // h buffer read at even t
    __bf16*       __restrict__ hbuf1, // h buffer read at odd t
    float*        __restrict__ out,
    unsigned*    sync,                // slots[4][64]*32 words, then rel[4]*32 words
    int t0) {
  __shared__ float Gp[4][4][16][17];  // [wave][gate][brow][jcol]

  const int tid  = threadIdx.x;
  const int lane = tid & 63;
  const int w    = tid >> 6;          // K-slice index

  // XCD-pair group mapping: lin%8 = XCD; bt = XCD>>1; 64 blocks per group
  const int lin = blockIdx.x;
  const int xcd = lin & 7;
  const int bt  = xcd >> 1;                      // batch group 0..3
  const int bx  = ((lin >> 3) << 1) | (xcd & 1); // j-tile 0..63 within group
  const int j0  = bx * 16;
  const int b0  = bt * 16;

  unsigned* slot_self = sync + (size_t)(bt * GRPB + bx) * 32;
  unsigned* grp_slots = sync + (size_t)bt * GRPB * 32;
  unsigned* rel       = sync + (size_t)4 * GRPB * 32 + bt * 32;

  // ---- preload W_hh fragments, PINNED in VGPRs for all 128 steps ----
  // lane (r=lane&15, q=lane>>4) holds Whh[g*1024 + j0 + r][w*256 + k*32 + q*8 .. +8]
  floatx4 wreg[32];
  {
    const int r = lane & 15, q = lane >> 4;
#pragma unroll
    for (int g = 0; g < 4; ++g)
#pragma unroll
      for (int k = 0; k < 8; ++k)
        wreg[g * 8 + k] = *reinterpret_cast<const floatx4*>(
            Whh + (size_t)(g * 1024 + j0 + r) * 1024 + (w * 8 + k) * 32 + q * 8);
  }
#pragma unroll
  for (int i = 0; i < 32; ++i)
    asm volatile("" : "+v"(wreg[i]));   // opaque def: compiler cannot re-sink loads

  // ---- per-thread (b,j) ownership for the elementwise update ----
  const int bb = tid >> 4, jj = tid & 15;
  const int gb = b0 + bb, gj = j0 + jj;
  float c = cst[gb * 1024 + gj];

  // A-frag base: lane holds h[b0+(lane&15)][w*256 + k*32 + (lane>>4)*8 .. +8]
  const int arow = (b0 + (lane & 15)) * 1024 + w * 256 + ((lane >> 4) * 8);
  const float* xrow = xp + (size_t)gb * TC * 4096 + gj;
  float* orow = out + (size_t)gb * (SEQ * HID) + gj;

  // prefetch xp for step 0
  float xi = xrow[0], xf = xrow[1024], xg = xrow[2048], xo = xrow[3072];

  for (int tt = 0; tt < TC; ++tt) {
    const int t = t0 + tt;
    const unsigned epoch = (unsigned)(t + 1);   // monotonic across chunks
    const __bf16* __restrict__ hin  = (t & 1) ? hbuf1 : hbuf0;
    __bf16*       __restrict__ hout = (t & 1) ? hbuf0 : hbuf1;

    // ---- h A-fragments (disjoint across waves) ----
    bf16x8 a[8];
#pragma unroll
    for (int k = 0; k < 8; ++k)
      a[k] = *reinterpret_cast<const bf16x8*>(hin + arow + k * 32);

    // ---- prefetch next step's xp (lands during barrier spin) ----
    float nxi = 0.f, nxf = 0.f, nxg = 0.f, nxo = 0.f;
    if (tt + 1 < TC) {
      const float* xr = xrow + (size_t)(tt + 1) * 4096;
      nxi = xr[0]; nxf = xr[1024]; nxg = xr[2048]; nxo = xr[3072];
    }

    // ---- 32 MFMAs: 4 independent chains (one per gate) of depth 8 ----
    floatx4 acc[4] = {};
#pragma unroll
    for (int k = 0; k < 8; ++k)
#pragma unroll
      for (int g = 0; g < 4; ++g)
        acc[g] = __builtin_amdgcn_mfma_f32_16x16x32_bf16(
            a[k], __builtin_bit_cast(bf16x8, wreg[g * 8 + k]), acc[g], 0, 0, 0);

    // ---- exchange K-slice partials through LDS ----
#pragma unroll
    for (int g = 0; g < 4; ++g)
#pragma unroll
      for (int r = 0; r < 4; ++r)
        Gp[w][g][(lane >> 4) * 4 + r][lane & 15] = acc[g][r];
    __syncthreads();

    float gi = Gp[0][0][bb][jj] + Gp[1][0][bb][jj] + Gp[2][0][bb][jj] + Gp[3][0][bb][jj] + xi;
    float gf = Gp[0][1][bb][jj] + Gp[1][1][bb][jj] + Gp[2][1][bb][jj] + Gp[3][1][bb][jj] + xf;
    float gg = Gp[0][2][bb][jj] + Gp[1][2][bb][jj] + Gp[2][2][bb][jj] + Gp[3][2][bb][jj] + xg;
    float go = Gp[0][3][bb][jj] + Gp[1][3][bb][jj] + Gp[2][3][bb][jj] + Gp[3][3][bb][jj] + xo;

    c = fast_sigm(gf) * c + fast_sigm(gi) * fast_tanh(gg);
    float h = fast_sigm(go) * fast_tanh(c);
    hout[gb * 1024 + gj] = (__bf16)h;          // critical-path store first
    orow[(size_t)t * HID] = h;
    if (t == SEQ - 1) {
      out[(size_t)SEQ * BATCH * HID + gb * HID + gj] = h;                 // h_n
      out[(size_t)SEQ * BATCH * HID + BATCH * HID + gb * HID + gj] = c;   // c_n
    }
    xi = nxi; xf = nxf; xg = nxg; xo = nxo;

    if (tt != TC - 1) {
      // ---- group barrier (64 blocks) ----
      __syncthreads();                         // all waves' h stores issued
      if (tid == 0)
        __hip_atomic_store(slot_self, epoch, __ATOMIC_RELEASE, __HIP_MEMORY_SCOPE_AGENT);
      if (bx == 0) {
        if (tid < 64) {                        // master wave: 64-lane slot sweep
          while (!__all(__hip_atomic_load(grp_slots + (size_t)tid * 32,
                                          __ATOMIC_RELAXED,
                                          __HIP_MEMORY_SCOPE_AGENT) >= epoch)) {}
          if (tid == 0) {
            __builtin_amdgcn_fence(__ATOMIC_ACQUIRE, "agent");
            __hip_atomic_store(rel, epoch, __ATOMIC_RELEASE, __HIP_MEMORY_SCOPE_AGENT);
          }
        }
      } else if (tid == 0) {
        while (__hip_atomic_load(rel, __ATOMIC_RELAXED, __HIP_MEMORY_SCOPE_AGENT) < epoch) {}
        __builtin_amdgcn_fence(__ATOMIC_ACQUIRE, "agent");
      }
      __syncthreads();                         // broadcast acquire to whole block
    }
  }

  cst[gb * 1024 + gj] = c;            // chunk-boundary state for next launch
}

// ---------------- host ----------------
extern "C" void kernel_launch(void* const* d_in, const int* in_sizes, int n_in,
                              void* d_out, int out_size, void* d_ws, size_t ws_size,
                              hipStream_t stream) {
  const float* inp = (const float*)d_in[0];
  const float* h0  = (const float*)d_in[1];
  const float* c0  = (const float*)d_in[2];
  const float* Wih = (const float*)d_in[3];
  const float* Whh = (const float*)d_in[4];
  const float* bih = (const float*)d_in[5];
  const float* bhh = (const float*)d_in[6];
  float* out = (float*)d_out;
  char* ws = (char*)d_ws;

  size_t off = 0;
  __bf16* Wih_b = (__bf16*)(ws + off); off += (size_t)GATES * HID * 2;        // 8 MB
  __bf16* Whh_b = (__bf16*)(ws + off); off += (size_t)GATES * HID * 2;        // 8 MB
  __bf16* x_b   = (__bf16*)(ws + off); off += (size_t)SEQ * BATCH * HID * 2;  // 64 MB
  float*  xp    = (float*)(ws + off);  off += (size_t)BATCH * TC * GATES * 4; // 128 MB
  float*  bias  = (float*)(ws + off);  off += (size_t)GATES * 4;
  float*  cst   = (float*)(ws + off);  off += (size_t)BATCH * HID * 4;
  __bf16* hb0   = (__bf16*)(ws + off); off += (size_t)BATCH * HID * 2;
  __bf16* hb1   = (__bf16*)(ws + off); off += (size_t)BATCH * HID * 2;
  const size_t sync_bytes = (size_t)(4 * GRPB * 32 + 4 * 32) * sizeof(unsigned);
  unsigned* sync = (unsigned*)(ws + off); off += sync_bytes;                  // 33 KB
  if (ws_size < off) return;  // ws too small: fail cleanly (diagnosable)

  int n4;
  n4 = GATES * HID / 4;
  cast_f32_to_bf16_x4<<<(n4 + 255) / 256, 256, 0, stream>>>(Wih, Wih_b, n4);
  cast_f32_to_bf16_x4<<<(n4 + 255) / 256, 256, 0, stream>>>(Whh, Whh_b, n4);
  n4 = SEQ * BATCH * HID / 4;
  cast_f32_to_bf16_x4<<<(n4 + 255) / 256, 256, 0, stream>>>(inp, x_b, n4);
  n4 = BATCH * HID / 4;
  cast_f32_to_bf16_x4<<<(n4 + 255) / 256, 256, 0, stream>>>(h0, hb0, n4);
  bias_sum<<<GATES / 256, 256, 0, stream>>>(bih, bhh, bias);
  hipMemcpyAsync(cst, c0, (size_t)BATCH * HID * 4, hipMemcpyDeviceToDevice, stream);
  hipMemsetAsync(sync, 0, sync_bytes, stream);   // epochs are monotonic: zero once

  __bf16* hbuf[2] = {hb0, hb1};
  bool coop_ok = true;
  for (int chunk = 0; chunk < SEQ / TC; ++chunk) {
    int t0 = chunk * TC;
    gemm_xproj<<<dim3(BATCH, GATES / 128), 256, 0, stream>>>(x_b, Wih_b, bias, xp, t0);
    if (coop_ok) {
      void* args[] = {(void*)&Whh_b, (void*)&xp, (void*)&cst, (void*)&hb0,
                      (void*)&hb1, (void*)&out, (void*)&sync, (void*)&t0};
      if (hipLaunchCooperativeKernel((const void*)lstm_persist, dim3(NBLK),
                                     dim3(256, 1, 1), args, 0, stream) != hipSuccess)
        coop_ok = false;
    }
    if (!coop_ok) {
      for (int tt = 0; tt < TC; ++tt) {
        int t = t0 + tt;
        lstm_step<<<dim3(HID / 16, BATCH / 16), 256, 0, stream>>>(
            hbuf[t & 1], hbuf[(t + 1) & 1], cst, Whh_b, xp, out, t);
      }
    }
  }
}